// Round 8
// baseline (467.039 us; speedup 1.0000x reference)
//
#include <hip/hip_runtime.h>
#include <stdint.h>

#define D_K 512
#define C_CLS 85742
#define N_PART 1340            // one partial per (row, 64-col block)

using bf16x8 = __attribute__((ext_vector_type(8))) short;
using f32x4  = __attribute__((ext_vector_type(4))) float;

// v_cvt_pk_bf16_f32: dst = {lo: bf16(a), hi: bf16(b)}, RNE. No builtin on
// gfx950 (m240) -> inline asm, non-volatile so the scheduler can move it.
__device__ __forceinline__ unsigned int cvtpk(float a, float b) {
  unsigned int r;
  asm("v_cvt_pk_bf16_f32 %0, %1, %2" : "=v"(r) : "v"(a), "v"(b));
  return r;
}
__device__ __forceinline__ unsigned short f2bf(float f) {
  unsigned int u = __builtin_bit_cast(unsigned int, f);
  u += 0x7FFFu + ((u >> 16) & 1u);          // round-to-nearest-even
  return (unsigned short)(u >> 16);
}
__device__ __forceinline__ float bf2f(unsigned short h) {
  return __builtin_bit_cast(float, ((unsigned int)h) << 16);
}
__device__ __forceinline__ float sq8(const float4& a, const float4& b) {
  return a.x*a.x + a.y*a.y + a.z*a.z + a.w*a.w +
         b.x*b.x + b.y*b.y + b.z*b.z + b.w*b.w;
}

// ---------------- Pass A: normalize x -> bf16 xn, save ||x|| ----------------
__global__ __launch_bounds__(256) void k_xnorm(const float* __restrict__ X,
                                               unsigned short* __restrict__ XN,
                                               float* __restrict__ FN) {
  int row  = blockIdx.x * 4 + (threadIdx.x >> 6);
  int lane = threadIdx.x & 63;
  const float4* px = (const float4*)(X + (size_t)row * D_K + lane * 8);
  float4 u = px[0], v = px[1];
  float nsq = sq8(u, v);
#pragma unroll
  for (int m = 1; m <= 32; m <<= 1) nsq += __shfl_xor(nsq, m);
  float nrm = sqrtf(nsq);
  float inv = 1.0f / fmaxf(nrm, 1e-12f);
  uint4 o;
  o.x = cvtpk(u.x*inv, u.y*inv); o.y = cvtpk(u.z*inv, u.w*inv);
  o.z = cvtpk(v.x*inv, v.y*inv); o.w = cvtpk(v.z*inv, v.w*inv);
  *(uint4*)(XN + (size_t)row * D_K + lane * 8) = o;
  if (lane == 0) FN[row] = nrm;
}

// ---- Pass C: barrier-free 512x64 MFMA block. 1024 thr / 16 waves; wave-tile
// ---- 32x64 (acc[2][4]); block covers FULL M=512 so W is read ONCE device-
// ---- wide. ZERO LDS, ZERO __syncthreads: each wave loads its own A frags
// ---- (XN bf16, L2-hot) and B frags (W fp32 -> v_cvt_pk in-reg) straight from
// ---- global; the 16 waves' identical B addresses hit L1. Waves free-run ->
// ---- latency hidden by TLP instead of barrier-lockstep prefetch.
// ---- Fused per-row ||w||^2 in registers (shfl-reduced over the 4 g-groups).
// ---- Epilogue: per-(row, 64col) (max, sumexp) partials of z=clamp(cos)*||x||.
__global__ __launch_bounds__(1024) void k_gemm_lse(const float* __restrict__ W,
                                                   const unsigned short* __restrict__ XN,
                                                   const float* __restrict__ FN,
                                                   float2* __restrict__ PART) {
  int bid = blockIdx.x;
  int n0 = bid * 64;

  int t    = threadIdx.x;
  int lane = t & 63, wid = t >> 6;          // 16 waves, wave = 32 M-rows
  int s = lane & 15, g = lane >> 4;
  int mrow = wid * 32;

  // B pointers: rows n0 + nf*16 + s (clamped), cols g*8.. (8 f32 per frag)
  const float* pB0; const float* pB1; const float* pB2; const float* pB3;
  {
    int r0 = n0 + s;      if (r0 > C_CLS - 1) r0 = C_CLS - 1;
    int r1 = n0 + 16 + s; if (r1 > C_CLS - 1) r1 = C_CLS - 1;
    int r2 = n0 + 32 + s; if (r2 > C_CLS - 1) r2 = C_CLS - 1;
    int r3 = n0 + 48 + s; if (r3 > C_CLS - 1) r3 = C_CLS - 1;
    pB0 = W + (size_t)r0 * D_K + g * 8;
    pB1 = W + (size_t)r1 * D_K + g * 8;
    pB2 = W + (size_t)r2 * D_K + g * 8;
    pB3 = W + (size_t)r3 * D_K + g * 8;
  }
  // A pointers: rows mrow + mf*16 + s, cols g*8.. (bf16x8 per frag)
  const unsigned short* pA0 = XN + (size_t)(mrow + s) * D_K + g * 8;
  const unsigned short* pA1 = XN + (size_t)(mrow + 16 + s) * D_K + g * 8;

  f32x4 acc[2][4] = {};
  float nsq0 = 0.f, nsq1 = 0.f, nsq2 = 0.f, nsq3 = 0.f;

#pragma unroll 2
  for (int kt = 0; kt < 16; ++kt) {
    // A frags (16B each, L2-hot)
    bf16x8 a0 = *(const bf16x8*)(pA0 + kt * 32);
    bf16x8 a1 = *(const bf16x8*)(pA1 + kt * 32);
    // B frags: 8 f32 -> 4 cvt_pk -> bf16x8, + ||w||^2 accumulation
    bf16x8 bfr[4];
#define LOADB(idx, ptr, nsqv) do { \
    float4 w0_ = *(const float4*)((ptr) + kt * 32); \
    float4 w1_ = *(const float4*)((ptr) + kt * 32 + 4); \
    nsqv += sq8(w0_, w1_); \
    uint4 u_; \
    u_.x = cvtpk(w0_.x, w0_.y); u_.y = cvtpk(w0_.z, w0_.w); \
    u_.z = cvtpk(w1_.x, w1_.y); u_.w = cvtpk(w1_.z, w1_.w); \
    bfr[idx] = __builtin_bit_cast(bf16x8, u_); \
  } while (0)
    LOADB(0, pB0, nsq0);
    LOADB(1, pB1, nsq1);
    LOADB(2, pB2, nsq2);
    LOADB(3, pB3, nsq3);
#undef LOADB
#pragma unroll
    for (int nf = 0; nf < 4; ++nf) {
      acc[0][nf] = __builtin_amdgcn_mfma_f32_16x16x32_bf16(a0, bfr[nf], acc[0][nf], 0, 0, 0);
      acc[1][nf] = __builtin_amdgcn_mfma_f32_16x16x32_bf16(a1, bfr[nf], acc[1][nf], 0, 0, 0);
    }
  }

  // finish ||w||^2: each row's k-range is split across the 4 g-groups
  nsq0 += __shfl_xor(nsq0, 16); nsq0 += __shfl_xor(nsq0, 32);
  nsq1 += __shfl_xor(nsq1, 16); nsq1 += __shfl_xor(nsq1, 32);
  nsq2 += __shfl_xor(nsq2, 16); nsq2 += __shfl_xor(nsq2, 32);
  nsq3 += __shfl_xor(nsq3, 16); nsq3 += __shfl_xor(nsq3, 32);

  float rinv[4]; int cvalid[4];
  rinv[0] = 1.0f / fmaxf(sqrtf(nsq0), 1e-12f);
  rinv[1] = 1.0f / fmaxf(sqrtf(nsq1), 1e-12f);
  rinv[2] = 1.0f / fmaxf(sqrtf(nsq2), 1e-12f);
  rinv[3] = 1.0f / fmaxf(sqrtf(nsq3), 1e-12f);
#pragma unroll
  for (int nf = 0; nf < 4; ++nf) cvalid[nf] = (n0 + nf * 16 + s) < C_CLS;

  const float NEG_INF = -__builtin_inff();
#pragma unroll
  for (int mf = 0; mf < 2; ++mf) {
#pragma unroll
    for (int q = 0; q < 4; ++q) {
      int rl = mrow + mf * 16 + g * 4 + q;        // D row = (lane>>4)*4+reg
      float fr = FN[rl];                          // L1/L2-hot scalar-ish load
      float z[4]; float mx = NEG_INF;
#pragma unroll
      for (int nf = 0; nf < 4; ++nf) {
        float cc = acc[mf][nf][q] * rinv[nf];
        cc = fminf(fmaxf(cc, -1.0f), 1.0f);
        z[nf] = cvalid[nf] ? cc * fr : NEG_INF;
        mx = fmaxf(mx, z[nf]);
      }
#pragma unroll
      for (int d = 1; d <= 8; d <<= 1) mx = fmaxf(mx, __shfl_xor(mx, d));
      float se = 0.f;
#pragma unroll
      for (int nf = 0; nf < 4; ++nf) se += __expf(z[nf] - mx);  // exp(-inf)=0
#pragma unroll
      for (int d = 1; d <= 8; d <<= 1) se += __shfl_xor(se, d);
      if (s == mf * 4 + q)
        PART[(size_t)rl * N_PART + bid] = make_float2(mx, se);
    }
  }
}

// ------- Pass D: per-row target logit (unmodified + margin-modified) --------
__global__ __launch_bounds__(64) void k_target(const float* __restrict__ W,
                                               const unsigned short* __restrict__ XN,
                                               const float* __restrict__ FN,
                                               const int* __restrict__ LBL,
                                               float2* __restrict__ ZT) {
  int row = blockIdx.x;
  int lane = threadIdx.x;
  int lab = LBL[row];
  const float* pw = W + (size_t)lab * D_K + lane * 8;
  const unsigned short* px = XN + (size_t)row * D_K + lane * 8;
  float dot = 0.f, nsq = 0.f;
#pragma unroll
  for (int j = 0; j < 8; ++j) {
    float w = pw[j];
    nsq += w * w;
    dot += bf2f(px[j]) * bf2f(f2bf(w));   // match GEMM numerics (bf16 operands)
  }
#pragma unroll
  for (int m = 1; m <= 32; m <<= 1) { dot += __shfl_xor(dot, m); nsq += __shfl_xor(nsq, m); }
  if (lane == 0) {
    const float LAMB = 1000.0f / 1.12f;   // iter=1 -> max(5, 1000/1.12)
    float rinv = 1.0f / fmaxf(sqrtf(nsq), 1e-12f);
    float c = fminf(fmaxf(dot * rinv, -1.0f), 1.0f);
    float c2 = c * c;
    float cm = 8.0f * c2 * c2 - 8.0f * c2 + 1.0f;   // cos(4θ)
    float th = acosf(c);
    float kf = floorf(4.0f * th / 3.14159265f);
    float phi = ((((int)kf) & 1) ? -cm : cm) - 2.0f * kf;
    float fr = FN[row];
    float zu = fr * c;
    float zm = fr * (c + (phi - c) / (1.0f + LAMB));
    ZT[row] = make_float2(zu, zm);
  }
}

// ------- Pass E1: combine 1340 partials per row -> per-row CE loss ----------
__global__ __launch_bounds__(256) void k_lse(const float2* __restrict__ PART,
                                             const float2* __restrict__ ZT,
                                             float* __restrict__ LOSSI) {
  int row = blockIdx.x;
  int t = threadIdx.x;
  const float NEG_INF = -__builtin_inff();
  float m = NEG_INF, ss = 0.f;
  for (int p = t; p < N_PART; p += 256) {
    float2 ps = PART[(size_t)row * N_PART + p];
    if (ps.y > 0.f) {
      if (ps.x > m) { ss = ss * __expf(m - ps.x) + ps.y; m = ps.x; }
      else          { ss += ps.y * __expf(ps.x - m); }
    }
  }
  __shared__ float sm[256], sv[256];
  sm[t] = m; sv[t] = ss;
  __syncthreads();
  for (int o = 128; o > 0; o >>= 1) {
    if (t < o) {
      float m1 = sm[t], s1 = sv[t];
      float m2 = sm[t + o], s2 = sv[t + o];
      float mm = fmaxf(m1, m2);
      float e1 = (m1 > NEG_INF) ? s1 * __expf(m1 - mm) : 0.f;
      float e2 = (m2 > NEG_INF) ? s2 * __expf(m2 - mm) : 0.f;
      sm[t] = mm; sv[t] = e1 + e2;
    }
    __syncthreads();
  }
  if (t == 0) {
    float M = sm[0], S = sv[0];
    float2 zt = ZT[row];
    // swap the target's unmodified exp term for the margin-modified one
    S += __expf(zt.y - M) - __expf(zt.x - M);
    LOSSI[row] = M + logf(S) - zt.y;
  }
}

// ------- Pass E2: mean over 512 rows -> scalar loss -------------------------
__global__ __launch_bounds__(256) void k_mean(const float* __restrict__ LOSSI,
                                              float* __restrict__ OUT) {
  int t = threadIdx.x;
  float s_ = LOSSI[t] + LOSSI[t + 256];
#pragma unroll
  for (int m = 1; m <= 32; m <<= 1) s_ += __shfl_xor(s_, m);
  __shared__ float wsum[4];
  if ((t & 63) == 0) wsum[t >> 6] = s_;
  __syncthreads();
  if (t == 0) OUT[0] = (wsum[0] + wsum[1] + wsum[2] + wsum[3]) * (1.0f / 512.0f);
}

extern "C" void kernel_launch(void* const* d_in, const int* in_sizes, int n_in,
                              void* d_out, int out_size, void* d_ws, size_t ws_size,
                              hipStream_t stream) {
  const float* X   = (const float*)d_in[0];   // [512,512] f32
  const float* W   = (const float*)d_in[1];   // [85742,512] f32
  const int*   LBL = (const int*)d_in[2];     // [512] i32
  float* OUT = (float*)d_out;

  char* ws = (char*)d_ws;
  unsigned short* XN = (unsigned short*)ws;            // 512*512*2       = 524288
  float*  FN    = (float*)(ws + 524288);               // 512*4           = 2048
  float2* ZT    = (float2*)(ws + 526336);              // 512*8           = 4096
  float*  LOSSI = (float*)(ws + 530432);               // 512*4           = 2048
  float2* PART  = (float2*)(ws + 532480);              // 512*1340*8      = 5488640

  k_xnorm  <<<dim3(128),  dim3(256),  0, stream>>>(X, XN, FN);
  k_gemm_lse<<<dim3(1340), dim3(1024), 0, stream>>>(W, XN, FN, PART);
  k_target <<<dim3(512),  dim3(64),   0, stream>>>(W, XN, FN, LBL, ZT);
  k_lse    <<<dim3(512),  dim3(256),  0, stream>>>(PART, ZT, LOSSI);
  k_mean   <<<dim3(1),    dim3(256),  0, stream>>>(LOSSI, OUT);
}

// Round 9
// 168.067 us; speedup vs baseline: 2.7789x; 2.7789x over previous
//
#include <hip/hip_runtime.h>
#include <stdint.h>

#define D_K 512
#define C_CLS 85742
#define N_TILES 670            // ceil(85742/128)
#define N_PART (N_TILES * 2)

using bf16x8 = __attribute__((ext_vector_type(8))) short;
using f32x4  = __attribute__((ext_vector_type(4))) float;

// v_cvt_pk_bf16_f32: dst = {lo: bf16(a), hi: bf16(b)}, RNE. No builtin on
// gfx950 (m240) -> inline asm, non-volatile so the scheduler can move it.
__device__ __forceinline__ unsigned int cvtpk(float a, float b) {
  unsigned int r;
  asm("v_cvt_pk_bf16_f32 %0, %1, %2" : "=v"(r) : "v"(a), "v"(b));
  return r;
}
__device__ __forceinline__ unsigned short f2bf(float f) {
  unsigned int u = __builtin_bit_cast(unsigned int, f);
  u += 0x7FFFu + ((u >> 16) & 1u);          // round-to-nearest-even
  return (unsigned short)(u >> 16);
}
__device__ __forceinline__ float bf2f(unsigned short h) {
  return __builtin_bit_cast(float, ((unsigned int)h) << 16);
}
__device__ __forceinline__ float sq8(const float4& a, const float4& b) {
  return a.x*a.x + a.y*a.y + a.z*a.z + a.w*a.w +
         b.x*b.x + b.y*b.y + b.z*b.z + b.w*b.w;
}

// ---------------- Pass A: normalize x -> bf16 xn, save ||x|| ----------------
__global__ __launch_bounds__(256) void k_xnorm(const float* __restrict__ X,
                                               unsigned short* __restrict__ XN,
                                               float* __restrict__ FN) {
  int row  = blockIdx.x * 4 + (threadIdx.x >> 6);
  int lane = threadIdx.x & 63;
  const float4* px = (const float4*)(X + (size_t)row * D_K + lane * 8);
  float4 u = px[0], v = px[1];
  float nsq = sq8(u, v);
#pragma unroll
  for (int m = 1; m <= 32; m <<= 1) nsq += __shfl_xor(nsq, m);
  float nrm = sqrtf(nsq);
  float inv = 1.0f / fmaxf(nrm, 1e-12f);
  uint4 o;
  o.x = cvtpk(u.x*inv, u.y*inv); o.y = cvtpk(u.z*inv, u.w*inv);
  o.z = cvtpk(v.x*inv, v.y*inv); o.w = cvtpk(v.z*inv, v.w*inv);
  *(uint4*)(XN + (size_t)row * D_K + lane * 8) = o;
  if (lane == 0) FN[row] = nrm;
}

// ---- Pass C: 128x128 bf16 MFMA GEMM, ALL-glds staging + consume-side cvt.
// ---- 256 thr / 4 waves (2x2), wave-tile 64x64, BK=32. A staged bf16 linear
// ---- (r5 layout, benign conflicts); B staged RAW fp32 via global_load_lds
// ---- with XOR chunk-swizzle k^(row&7) on the per-lane GLOBAL source (rule
// ---- 21: swizzle source + read, LDS dest stays linear). fp32->bf16 cvt_pk
// ---- happens at consume time in FRAGS; ||w||^2 accumulates per-lane from
// ---- the same f32 values (no LDS nsq, no extra syncs). 3 LDS buffers,
// ---- counted vmcnt(6) barriers: loads issue one FULL K-step early and only
// ---- the one-step-old group is drained at each barrier.
// ---- Epilogue: per-(row,64col) (max,sumexp) partials of z=clamp(cos)*||x||.
__global__ __launch_bounds__(256) void k_gemm_lse(const float* __restrict__ W,
                                                  const unsigned short* __restrict__ XN,
                                                  const float* __restrict__ FN,
                                                  float2* __restrict__ PART) {
  __shared__ alignas(16) unsigned short As[3][4096];   // 3 x 8KB  (128 x 32 bf16)
  __shared__ alignas(16) float          Bs[3][4096];   // 3 x 16KB (128 x 32 f32)

  int bid = blockIdx.x;
  // bijective XCD chunking: 2680 = 8*335; 4 m-blocks of an n-tile stay on one XCD
  int wg    = (bid & 7) * 335 + (bid >> 3);
  int ntile = wg >> 2, mtile = wg & 3;
  int m0 = mtile * 128, n0 = ntile * 128;

  int t    = threadIdx.x;
  int lane = t & 63, wid = t >> 6;
  int wm = wid >> 1, wn = wid & 1;
  int s = lane & 15, g = lane >> 4;

  // A glds source (r5-proven): instr j covers rows wid*16 + j*64 + (lane>>2),
  // col (lane&3)*8; LDS dest linear at wid*512 (+2048 for j=1).
  const unsigned short* gA0 = XN + (size_t)(m0 + wid * 16 + (lane >> 2)) * D_K + (lane & 3) * 8;

  // B glds sources, swizzled: instr j covers 16B-chunk c = (wid*4+j)*64+lane;
  // row r = c>>3, stored chunk k = c&7, logical chunk kl = k^(r&7).
  // Global src = W[clamp(n0+r)][kl*4 + kt*32]; LDS dest linear.
  const float* pB0; const float* pB1; const float* pB2; const float* pB3;
  {
#define BSRC(j, dst) do { \
    int c_ = ((wid * 4 + (j)) * 64) + lane; \
    int r_ = c_ >> 3, k_ = c_ & 7; \
    int kl_ = k_ ^ (r_ & 7); \
    int gr_ = n0 + r_; if (gr_ > C_CLS - 1) gr_ = C_CLS - 1; \
    dst = W + (size_t)gr_ * D_K + kl_ * 4; \
  } while (0)
    BSRC(0, pB0); BSRC(1, pB1); BSRC(2, pB2); BSRC(3, pB3);
#undef BSRC
  }

  f32x4 acc[4][4] = {};
  float nsq[4] = {0.f, 0.f, 0.f, 0.f};   // per-lane ||w||^2 partials (row nf, slice g)

#define GLDS(srcp, dstp) __builtin_amdgcn_global_load_lds( \
    (const __attribute__((address_space(1))) unsigned int*)(srcp), \
    (__attribute__((address_space(3))) unsigned int*)(dstp), 16, 0, 0)

  // 6 glds per thread-step: 2 for A (8KB), 4 for B (16KB raw f32)
#define STAGE(b, kk) do { \
    GLDS(gA0 + (size_t)(kk) * 32,            &As[b][wid * 512]); \
    GLDS(gA0 + 64 * D_K + (size_t)(kk) * 32, &As[b][2048 + wid * 512]); \
    GLDS(pB0 + (size_t)(kk) * 32, &Bs[b][(wid * 4 + 0) * 256]); \
    GLDS(pB1 + (size_t)(kk) * 32, &Bs[b][(wid * 4 + 1) * 256]); \
    GLDS(pB2 + (size_t)(kk) * 32, &Bs[b][(wid * 4 + 2) * 256]); \
    GLDS(pB3 + (size_t)(kk) * 32, &Bs[b][(wid * 4 + 3) * 256]); \
  } while (0)

  // FRAGS: A frags linear; B frags = 2 swizzled b128 f32 reads + 4 cvt_pk
  // (+8 nsq FMAs) per frag. Logical chunks {2g, 2g+1} stored at {2g^m, (2g^m)^1}
  // where m = row&7.
#define FRAGS_MFMA(b) do { \
    bf16x8 af[4], bfr[4]; \
    _Pragma("unroll") for (int mf = 0; mf < 4; ++mf) \
      af[mf] = *(const bf16x8*)(&As[b][(wm * 64 + mf * 16 + s) * 32 + g * 8]); \
    _Pragma("unroll") for (int nf = 0; nf < 4; ++nf) { \
      int R_ = wn * 64 + nf * 16 + s; \
      int p0_ = (2 * g) ^ (R_ & 7); \
      const float4* q0_ = (const float4*)(&Bs[b][R_ * 32 + p0_ * 4]); \
      const float4* q1_ = (const float4*)(&Bs[b][R_ * 32 + (p0_ ^ 1) * 4]); \
      float4 w0_ = *q0_, w1_ = *q1_; \
      nsq[nf] += sq8(w0_, w1_); \
      uint4 u_; \
      u_.x = cvtpk(w0_.x, w0_.y); u_.y = cvtpk(w0_.z, w0_.w); \
      u_.z = cvtpk(w1_.x, w1_.y); u_.w = cvtpk(w1_.z, w1_.w); \
      bfr[nf] = __builtin_bit_cast(bf16x8, u_); \
    } \
    _Pragma("unroll") for (int mf = 0; mf < 4; ++mf) \
      _Pragma("unroll") for (int nf = 0; nf < 4; ++nf) \
        acc[mf][nf] = __builtin_amdgcn_mfma_f32_16x16x32_bf16(af[mf], bfr[nf], acc[mf][nf], 0, 0, 0); \
  } while (0)

  // counted barrier: 12 outstanding glds {6 just issued, 6 one step old};
  // drain only the old group. lgkmcnt(0) is already satisfied (compiler waits
  // before the MFMAs) - included for safety.
#define BARC() do { \
    asm volatile("s_waitcnt vmcnt(6) lgkmcnt(0)" ::: "memory"); \
    __builtin_amdgcn_s_barrier(); } while (0)
#define BAR0() do { \
    asm volatile("s_waitcnt vmcnt(0) lgkmcnt(0)" ::: "memory"); \
    __builtin_amdgcn_s_barrier(); } while (0)

  // ---- prologue: tiles 0,1 in flight; publish tile 0 ----
  STAGE(0, 0);
  STAGE(1, 1);
  BARC();                        // drain tile 0's 6; tile 1's stay in flight

  // ---- steady state: kt = 0..12 (stage kt+2, compute kt, drain kt+1) ----
  for (int kt = 0; kt < 13; ++kt) {
    int cur = kt % 3;
    int nxt = (kt + 2) % 3;
    STAGE(nxt, kt + 2);
    FRAGS_MFMA(cur);
    BARC();
  }
  // kt = 13: stage(15), compute 13, drain 14
  STAGE(0, 15);
  FRAGS_MFMA(1);
  BARC();
  // kt = 14: compute 14, drain 15
  FRAGS_MFMA(2);
  BAR0();
  // kt = 15
  FRAGS_MFMA(0);

  // ---- finish ||w||^2: slices split across g-groups; reduce over g ----
#pragma unroll
  for (int nf = 0; nf < 4; ++nf) {
    nsq[nf] += __shfl_xor(nsq[nf], 16);
    nsq[nf] += __shfl_xor(nsq[nf], 32);
  }
  float rinv[4]; int cvalid[4];
#pragma unroll
  for (int nf = 0; nf < 4; ++nf) {
    cvalid[nf] = (n0 + wn * 64 + nf * 16 + s) < C_CLS;
    rinv[nf] = 1.0f / fmaxf(sqrtf(nsq[nf]), 1e-12f);
  }
  const float NEG_INF = -__builtin_inff();
#pragma unroll
  for (int mf = 0; mf < 4; ++mf) {
#pragma unroll
    for (int q = 0; q < 4; ++q) {
      int rl = wm * 64 + mf * 16 + g * 4 + q;     // D row = (lane>>4)*4+reg
      float fr = FN[m0 + rl];
      float z[4]; float mx = NEG_INF;
#pragma unroll
      for (int nf = 0; nf < 4; ++nf) {
        float cc = acc[mf][nf][q] * rinv[nf];
        cc = fminf(fmaxf(cc, -1.0f), 1.0f);
        z[nf] = cvalid[nf] ? cc * fr : NEG_INF;
        mx = fmaxf(mx, z[nf]);
      }
#pragma unroll
      for (int d = 1; d <= 8; d <<= 1) mx = fmaxf(mx, __shfl_xor(mx, d));
      float se = 0.f;
#pragma unroll
      for (int nf = 0; nf < 4; ++nf) se += __expf(z[nf] - mx);  // exp(-inf)=0
#pragma unroll
      for (int d = 1; d <= 8; d <<= 1) se += __shfl_xor(se, d);
      if (s == mf * 4 + q)
        PART[(size_t)(m0 + rl) * N_PART + (ntile * 2 + wn)] = make_float2(mx, se);
    }
  }
}

// ------- Pass D: per-row target logit (unmodified + margin-modified) --------
__global__ __launch_bounds__(64) void k_target(const float* __restrict__ W,
                                               const unsigned short* __restrict__ XN,
                                               const float* __restrict__ FN,
                                               const int* __restrict__ LBL,
                                               float2* __restrict__ ZT) {
  int row = blockIdx.x;
  int lane = threadIdx.x;
  int lab = LBL[row];
  const float* pw = W + (size_t)lab * D_K + lane * 8;
  const unsigned short* px = XN + (size_t)row * D_K + lane * 8;
  float dot = 0.f, nsq = 0.f;
#pragma unroll
  for (int j = 0; j < 8; ++j) {
    float w = pw[j];
    nsq += w * w;
    dot += bf2f(px[j]) * bf2f(f2bf(w));   // match GEMM numerics (bf16 operands)
  }
#pragma unroll
  for (int m = 1; m <= 32; m <<= 1) { dot += __shfl_xor(dot, m); nsq += __shfl_xor(nsq, m); }
  if (lane == 0) {
    const float LAMB = 1000.0f / 1.12f;   // iter=1 -> max(5, 1000/1.12)
    float rinv = 1.0f / fmaxf(sqrtf(nsq), 1e-12f);
    float c = fminf(fmaxf(dot * rinv, -1.0f), 1.0f);
    float c2 = c * c;
    float cm = 8.0f * c2 * c2 - 8.0f * c2 + 1.0f;   // cos(4θ)
    float th = acosf(c);
    float kf = floorf(4.0f * th / 3.14159265f);
    float phi = ((((int)kf) & 1) ? -cm : cm) - 2.0f * kf;
    float fr = FN[row];
    float zu = fr * c;
    float zm = fr * (c + (phi - c) / (1.0f + LAMB));
    ZT[row] = make_float2(zu, zm);
  }
}

// ------- Pass E1: combine 1340 partials per row -> per-row CE loss ----------
__global__ __launch_bounds__(256) void k_lse(const float2* __restrict__ PART,
                                             const float2* __restrict__ ZT,
                                             float* __restrict__ LOSSI) {
  int row = blockIdx.x;
  int t = threadIdx.x;
  const float NEG_INF = -__builtin_inff();
  float m = NEG_INF, ss = 0.f;
  for (int p = t; p < N_PART; p += 256) {
    float2 ps = PART[(size_t)row * N_PART + p];
    if (ps.y > 0.f) {
      if (ps.x > m) { ss = ss * __expf(m - ps.x) + ps.y; m = ps.x; }
      else          { ss += ps.y * __expf(ps.x - m); }
    }
  }
  __shared__ float sm[256], sv[256];
  sm[t] = m; sv[t] = ss;
  __syncthreads();
  for (int o = 128; o > 0; o >>= 1) {
    if (t < o) {
      float m1 = sm[t], s1 = sv[t];
      float m2 = sm[t + o], s2 = sv[t + o];
      float mm = fmaxf(m1, m2);
      float e1 = (m1 > NEG_INF) ? s1 * __expf(m1 - mm) : 0.f;
      float e2 = (m2 > NEG_INF) ? s2 * __expf(m2 - mm) : 0.f;
      sm[t] = mm; sv[t] = e1 + e2;
    }
    __syncthreads();
  }
  if (t == 0) {
    float M = sm[0], S = sv[0];
    float2 zt = ZT[row];
    // swap the target's unmodified exp term for the margin-modified one
    S += __expf(zt.y - M) - __expf(zt.x - M);
    LOSSI[row] = M + logf(S) - zt.y;
  }
}

// ------- Pass E2: mean over 512 rows -> scalar loss -------------------------
__global__ __launch_bounds__(256) void k_mean(const float* __restrict__ LOSSI,
                                              float* __restrict__ OUT) {
  int t = threadIdx.x;
  float s_ = LOSSI[t] + LOSSI[t + 256];
#pragma unroll
  for (int m = 1; m <= 32; m <<= 1) s_ += __shfl_xor(s_, m);
  __shared__ float wsum[4];
  if ((t & 63) == 0) wsum[t >> 6] = s_;
  __syncthreads();
  if (t == 0) OUT[0] = (wsum[0] + wsum[1] + wsum[2] + wsum[3]) * (1.0f / 512.0f);
}

extern "C" void kernel_launch(void* const* d_in, const int* in_sizes, int n_in,
                              void* d_out, int out_size, void* d_ws, size_t ws_size,
                              hipStream_t stream) {
  const float* X   = (const float*)d_in[0];   // [512,512] f32
  const float* W   = (const float*)d_in[1];   // [85742,512] f32
  const int*   LBL = (const int*)d_in[2];     // [512] i32
  float* OUT = (float*)d_out;

  char* ws = (char*)d_ws;
  unsigned short* XN = (unsigned short*)ws;            // 512*512*2       = 524288
  float*  FN    = (float*)(ws + 524288);               // 512*4           = 2048
  float2* ZT    = (float2*)(ws + 526336);              // 512*8           = 4096
  float*  LOSSI = (float*)(ws + 530432);               // 512*4           = 2048
  float2* PART  = (float2*)(ws + 532480);              // 512*1340*8      = 5488640

  k_xnorm  <<<dim3(128),  dim3(256), 0, stream>>>(X, XN, FN);
  k_gemm_lse<<<dim3(2680), dim3(256), 0, stream>>>(W, XN, FN, PART);
  k_target <<<dim3(512),  dim3(64),  0, stream>>>(W, XN, FN, LBL, ZT);
  k_lse    <<<dim3(512),  dim3(256), 0, stream>>>(PART, ZT, LOSSI);
  k_mean   <<<dim3(1),    dim3(256), 0, stream>>>(LOSSI, OUT);
}

// Round 10
// 131.967 us; speedup vs baseline: 3.5391x; 1.2736x over previous
//
#include <hip/hip_runtime.h>
#include <stdint.h>

#define D_K 512
#define C_CLS 85742
#define N_TILES 670            // ceil(85742/128)
#define N_PART (N_TILES * 2)

using bf16x8 = __attribute__((ext_vector_type(8))) short;
using f32x4  = __attribute__((ext_vector_type(4))) float;

// v_cvt_pk_bf16_f32: dst = {lo: bf16(a), hi: bf16(b)}, RNE. No builtin on
// gfx950 (m240) -> inline asm, non-volatile so the scheduler can move it.
__device__ __forceinline__ unsigned int cvtpk(float a, float b) {
  unsigned int r;
  asm("v_cvt_pk_bf16_f32 %0, %1, %2" : "=v"(r) : "v"(a), "v"(b));
  return r;
}
__device__ __forceinline__ unsigned short f2bf(float f) {
  unsigned int u = __builtin_bit_cast(unsigned int, f);
  u += 0x7FFFu + ((u >> 16) & 1u);          // round-to-nearest-even
  return (unsigned short)(u >> 16);
}
__device__ __forceinline__ float bf2f(unsigned short h) {
  return __builtin_bit_cast(float, ((unsigned int)h) << 16);
}
__device__ __forceinline__ float sq8(const float4& a, const float4& b) {
  return a.x*a.x + a.y*a.y + a.z*a.z + a.w*a.w +
         b.x*b.x + b.y*b.y + b.z*b.z + b.w*b.w;
}

#define GLDS(srcp, dstp) __builtin_amdgcn_global_load_lds( \
    (const __attribute__((address_space(1))) unsigned int*)(srcp), \
    (__attribute__((address_space(3))) unsigned int*)(dstp), 16, 0, 0)

// ---------------- Pass A: normalize x -> bf16 xn, save ||x|| ----------------
__global__ __launch_bounds__(256) void k_xnorm(const float* __restrict__ X,
                                               unsigned short* __restrict__ XN,
                                               float* __restrict__ FN) {
  int row  = blockIdx.x * 4 + (threadIdx.x >> 6);
  int lane = threadIdx.x & 63;
  const float4* px = (const float4*)(X + (size_t)row * D_K + lane * 8);
  float4 u = px[0], v = px[1];
  float nsq = sq8(u, v);
#pragma unroll
  for (int m = 1; m <= 32; m <<= 1) nsq += __shfl_xor(nsq, m);
  float nrm = sqrtf(nsq);
  float inv = 1.0f / fmaxf(nrm, 1e-12f);
  uint4 o;
  o.x = cvtpk(u.x*inv, u.y*inv); o.y = cvtpk(u.z*inv, u.w*inv);
  o.z = cvtpk(v.x*inv, v.y*inv); o.w = cvtpk(v.z*inv, v.w*inv);
  *(uint4*)(XN + (size_t)row * D_K + lane * 8) = o;
  if (lane == 0) FN[row] = nrm;
}

// ---- Pass B: W fp32 -> bf16 (RNE, bit-identical to in-loop conversion) +
// ---- fused ||w||^2 -> RINV = 1/max(||w||,eps). Pure memory-bound stream.
__global__ __launch_bounds__(256) void k_wnorm(const float* __restrict__ W,
                                               unsigned short* __restrict__ WBF,
                                               float* __restrict__ RINV) {
  int row  = blockIdx.x * 4 + (threadIdx.x >> 6);
  if (row >= C_CLS) return;
  int lane = threadIdx.x & 63;
  const float4* pw = (const float4*)(W + (size_t)row * D_K + lane * 8);
  float4 u = pw[0], v = pw[1];
  float nsq = sq8(u, v);
#pragma unroll
  for (int m = 1; m <= 32; m <<= 1) nsq += __shfl_xor(nsq, m);
  uint4 o;
  o.x = cvtpk(u.x, u.y); o.y = cvtpk(u.z, u.w);
  o.z = cvtpk(v.x, v.y); o.w = cvtpk(v.z, v.w);
  *(uint4*)(WBF + (size_t)row * D_K + lane * 8) = o;
  if (lane == 0) RINV[row] = 1.0f / fmaxf(sqrtf(nsq), 1e-12f);
}

// ---- Pass C (primary): pure-bf16 128x128 MFMA GEMM, m97 pattern. 256 thr /
// ---- 4 waves (2x2), wave-tile 64x64, BK=32, dbuf LDS, ONE barrier/K-step.
// ---- Loop body: 4 global_load_lds + 8 ds_read_b128 + 16 MFMA + barrier —
// ---- ZERO conversion VALU (W pre-converted by k_wnorm). Epilogue reads
// ---- precomputed RINV; emits per-(row,64col) (max,sumexp) partials.
__global__ __launch_bounds__(256) void k_gemm2(const unsigned short* __restrict__ WBF,
                                               const unsigned short* __restrict__ XN,
                                               const float* __restrict__ FN,
                                               const float* __restrict__ RINV,
                                               float2* __restrict__ PART) {
  __shared__ alignas(16) unsigned short As[2][4096];   // [buf][128 x 32 bf16]
  __shared__ alignas(16) unsigned short Bs[2][4096];

  int bid = blockIdx.x;
  // bijective XCD chunking: 2680 = 8*335; 4 m-blocks of an n-tile on one XCD
  int wg    = (bid & 7) * 335 + (bid >> 3);
  int ntile = wg >> 2, mtile = wg & 3;
  int m0 = mtile * 128, n0 = ntile * 128;

  int t    = threadIdx.x;
  int lane = t & 63, wid = t >> 6;
  int wm = wid >> 1, wn = wid & 1;
  int s = lane & 15, g = lane >> 4;

  // A glds sources (r5-proven): instr j covers rows wid*16 + j*64 + (lane>>2),
  // col (lane&3)*8; linear LDS dest wave base + lane*16.
  const unsigned short* gA0 = XN + (size_t)(m0 + wid * 16 + (lane >> 2)) * D_K + (lane & 3) * 8;
  const unsigned short* gA1 = gA0 + (size_t)64 * D_K;
  // B glds sources: same geometry over WBF, rows clamped (uniform, branch-free)
  int rB0 = n0 + wid * 16 + (lane >> 2); if (rB0 > C_CLS - 1) rB0 = C_CLS - 1;
  int rB1 = n0 + 64 + wid * 16 + (lane >> 2); if (rB1 > C_CLS - 1) rB1 = C_CLS - 1;
  const unsigned short* gB0 = WBF + (size_t)rB0 * D_K + (lane & 3) * 8;
  const unsigned short* gB1 = WBF + (size_t)rB1 * D_K + (lane & 3) * 8;

  f32x4 acc[4][4] = {};

#define STAGE(b, kk) do { \
    GLDS(gA0 + (size_t)(kk) * 32, &As[b][wid * 512]); \
    GLDS(gA1 + (size_t)(kk) * 32, &As[b][2048 + wid * 512]); \
    GLDS(gB0 + (size_t)(kk) * 32, &Bs[b][wid * 512]); \
    GLDS(gB1 + (size_t)(kk) * 32, &Bs[b][2048 + wid * 512]); \
  } while (0)

#define FRAGS_MFMA(b) do { \
    bf16x8 af[4], bfr[4]; \
    _Pragma("unroll") for (int mf = 0; mf < 4; ++mf) \
      af[mf] = *(const bf16x8*)(&As[b][(wm * 64 + mf * 16 + s) * 32 + g * 8]); \
    _Pragma("unroll") for (int nf = 0; nf < 4; ++nf) \
      bfr[nf] = *(const bf16x8*)(&Bs[b][(wn * 64 + nf * 16 + s) * 32 + g * 8]); \
    _Pragma("unroll") for (int mf = 0; mf < 4; ++mf) \
      _Pragma("unroll") for (int nf = 0; nf < 4; ++nf) \
        acc[mf][nf] = __builtin_amdgcn_mfma_f32_16x16x32_bf16(af[mf], bfr[nf], acc[mf][nf], 0, 0, 0); \
  } while (0)

  STAGE(0, 0);
  __syncthreads();
  for (int kt = 0; kt < 16; ++kt) {
    int cur = kt & 1;
    if (kt < 15) STAGE(cur ^ 1, kt + 1);   // async glds, covered by FRAGS below
    FRAGS_MFMA(cur);
    if (kt < 15) __syncthreads();          // drains glds; publishes other buffer
  }

  float rinv[4]; int cvalid[4];
#pragma unroll
  for (int nf = 0; nf < 4; ++nf) {
    int gc = n0 + wn * 64 + nf * 16 + s;
    cvalid[nf] = gc < C_CLS;
    rinv[nf] = RINV[cvalid[nf] ? gc : C_CLS - 1];
  }
  const float NEG_INF = -__builtin_inff();
#pragma unroll
  for (int mf = 0; mf < 4; ++mf) {
#pragma unroll
    for (int q = 0; q < 4; ++q) {
      int rl = wm * 64 + mf * 16 + g * 4 + q;     // D row = (lane>>4)*4+reg
      float fr = FN[m0 + rl];
      float z[4]; float mx = NEG_INF;
#pragma unroll
      for (int nf = 0; nf < 4; ++nf) {
        float cc = acc[mf][nf][q] * rinv[nf];
        cc = fminf(fmaxf(cc, -1.0f), 1.0f);
        z[nf] = cvalid[nf] ? cc * fr : NEG_INF;
        mx = fmaxf(mx, z[nf]);
      }
#pragma unroll
      for (int d = 1; d <= 8; d <<= 1) mx = fmaxf(mx, __shfl_xor(mx, d));
      float se = 0.f;
#pragma unroll
      for (int nf = 0; nf < 4; ++nf) se += __expf(z[nf] - mx);  // exp(-inf)=0
#pragma unroll
      for (int d = 1; d <= 8; d <<= 1) se += __shfl_xor(se, d);
      if (s == mf * 4 + q)
        PART[(size_t)(m0 + rl) * N_PART + (ntile * 2 + wn)] = make_float2(mx, se);
    }
  }
}

// ---- Pass C (fallback, ws too small): round-5 fused kernel, verbatim ----
__global__ __launch_bounds__(256) void k_gemm_fb(const float* __restrict__ W,
                                                 const unsigned short* __restrict__ XN,
                                                 const float* __restrict__ FN,
                                                 float2* __restrict__ PART) {
  __shared__ alignas(16) unsigned short As[2][4096];
  __shared__ alignas(16) unsigned short Bs[2][4096];
  __shared__ float nsqS[128];
  __shared__ float fnS[128];

  int bid = blockIdx.x;
  int wg    = (bid & 7) * 335 + (bid >> 3);
  int ntile = wg >> 2, mtile = wg & 3;
  int m0 = mtile * 128, n0 = ntile * 128;

  int t    = threadIdx.x;
  int lane = t & 63, wid = t >> 6;
  int wm = wid >> 1, wn = wid & 1;
  int s = lane & 15, g = lane >> 4;

  int r1 = t >> 2;
  int c0 = (t & 3) * 8;
  int gr1 = n0 + r1;      if (gr1 > C_CLS - 1) gr1 = C_CLS - 1;
  int gr2 = n0 + 64 + r1; if (gr2 > C_CLS - 1) gr2 = C_CLS - 1;
  const float* pB1 = W + (size_t)gr1 * D_K + c0;
  const float* pB2 = W + (size_t)gr2 * D_K + c0;

  const unsigned short* gA0 = XN + (size_t)(m0 + wid * 16 + (lane >> 2)) * D_K + (lane & 3) * 8;
  f32x4 acc[4][4] = {};
  float nsq1 = 0.f, nsq2 = 0.f;
  float4 ra0, ra1, rb0, rb1;

#define STAGE_A(b, kk) do { \
    GLDS(gA0 + (size_t)(kk) * 32,            &As[b][wid * 512]); \
    GLDS(gA0 + 64 * D_K + (size_t)(kk) * 32, &As[b][2048 + wid * 512]); \
  } while (0)
#define PREF_B(kk) do { \
    const float* q1_ = pB1 + (size_t)(kk) * 32; \
    const float* q2_ = pB2 + (size_t)(kk) * 32; \
    ra0 = *(const float4*)q1_; ra1 = *(const float4*)(q1_ + 4); \
    rb0 = *(const float4*)q2_; rb1 = *(const float4*)(q2_ + 4); \
  } while (0)
#define CONV_B(b) do { \
    nsq1 += sq8(ra0, ra1); \
    nsq2 += sq8(rb0, rb1); \
    uint4 u1_, u2_; \
    u1_.x = cvtpk(ra0.x, ra0.y); u1_.y = cvtpk(ra0.z, ra0.w); \
    u1_.z = cvtpk(ra1.x, ra1.y); u1_.w = cvtpk(ra1.z, ra1.w); \
    u2_.x = cvtpk(rb0.x, rb0.y); u2_.y = cvtpk(rb0.z, rb0.w); \
    u2_.z = cvtpk(rb1.x, rb1.y); u2_.w = cvtpk(rb1.z, rb1.w); \
    *(uint4*)(&Bs[b][t * 8])        = u1_; \
    *(uint4*)(&Bs[b][2048 + t * 8]) = u2_; \
  } while (0)

  STAGE_A(0, 0);
  PREF_B(0);
  if (t < 128) fnS[t] = FN[m0 + t];
  CONV_B(0);
  __syncthreads();
  for (int kt = 0; kt < 15; ++kt) {
    int cur = kt & 1;
    STAGE_A(cur ^ 1, kt + 1);
    PREF_B(kt + 1);
    FRAGS_MFMA(cur);
    CONV_B(cur ^ 1);
    __syncthreads();
  }
  FRAGS_MFMA(1);

  nsq1 += __shfl_xor(nsq1, 1); nsq1 += __shfl_xor(nsq1, 2);
  nsq2 += __shfl_xor(nsq2, 1); nsq2 += __shfl_xor(nsq2, 2);
  if ((t & 3) == 0) { nsqS[r1] = nsq1; nsqS[64 + r1] = nsq2; }
  __syncthreads();

  float rinv[4]; int cvalid[4];
#pragma unroll
  for (int nf = 0; nf < 4; ++nf) {
    int cl = wn * 64 + nf * 16 + s;
    cvalid[nf] = (n0 + cl) < C_CLS;
    rinv[nf] = 1.0f / fmaxf(sqrtf(nsqS[cl]), 1e-12f);
  }
  const float NEG_INF = -__builtin_inff();
#pragma unroll
  for (int mf = 0; mf < 4; ++mf) {
#pragma unroll
    for (int q = 0; q < 4; ++q) {
      int rl = wm * 64 + mf * 16 + g * 4 + q;
      float fr = fnS[rl];
      float z[4]; float mx = NEG_INF;
#pragma unroll
      for (int nf = 0; nf < 4; ++nf) {
        float cc = acc[mf][nf][q] * rinv[nf];
        cc = fminf(fmaxf(cc, -1.0f), 1.0f);
        z[nf] = cvalid[nf] ? cc * fr : NEG_INF;
        mx = fmaxf(mx, z[nf]);
      }
#pragma unroll
      for (int d = 1; d <= 8; d <<= 1) mx = fmaxf(mx, __shfl_xor(mx, d));
      float se = 0.f;
#pragma unroll
      for (int nf = 0; nf < 4; ++nf) se += __expf(z[nf] - mx);
#pragma unroll
      for (int d = 1; d <= 8; d <<= 1) se += __shfl_xor(se, d);
      if (s == mf * 4 + q)
        PART[(size_t)(m0 + rl) * N_PART + (ntile * 2 + wn)] = make_float2(mx, se);
    }
  }
}

// ------- Pass D: per-row target logit (unmodified + margin-modified) --------
__global__ __launch_bounds__(64) void k_target(const float* __restrict__ W,
                                               const unsigned short* __restrict__ XN,
                                               const float* __restrict__ FN,
                                               const int* __restrict__ LBL,
                                               float2* __restrict__ ZT) {
  int row = blockIdx.x;
  int lane = threadIdx.x;
  int lab = LBL[row];
  const float* pw = W + (size_t)lab * D_K + lane * 8;
  const unsigned short* px = XN + (size_t)row * D_K + lane * 8;
  float dot = 0.f, nsq = 0.f;
#pragma unroll
  for (int j = 0; j < 8; ++j) {
    float w = pw[j];
    nsq += w * w;
    dot += bf2f(px[j]) * bf2f(f2bf(w));   // match GEMM numerics (bf16 operands)
  }
#pragma unroll
  for (int m = 1; m <= 32; m <<= 1) { dot += __shfl_xor(dot, m); nsq += __shfl_xor(nsq, m); }
  if (lane == 0) {
    const float LAMB = 1000.0f / 1.12f;   // iter=1 -> max(5, 1000/1.12)
    float rinv = 1.0f / fmaxf(sqrtf(nsq), 1e-12f);
    float c = fminf(fmaxf(dot * rinv, -1.0f), 1.0f);
    float c2 = c * c;
    float cm = 8.0f * c2 * c2 - 8.0f * c2 + 1.0f;   // cos(4θ)
    float th = acosf(c);
    float kf = floorf(4.0f * th / 3.14159265f);
    float phi = ((((int)kf) & 1) ? -cm : cm) - 2.0f * kf;
    float fr = FN[row];
    float zu = fr * c;
    float zm = fr * (c + (phi - c) / (1.0f + LAMB));
    ZT[row] = make_float2(zu, zm);
  }
}

// ------- Pass E1: combine 1340 partials per row -> per-row CE loss ----------
__global__ __launch_bounds__(256) void k_lse(const float2* __restrict__ PART,
                                             const float2* __restrict__ ZT,
                                             float* __restrict__ LOSSI) {
  int row = blockIdx.x;
  int t = threadIdx.x;
  const float NEG_INF = -__builtin_inff();
  float m = NEG_INF, ss = 0.f;
  for (int p = t; p < N_PART; p += 256) {
    float2 ps = PART[(size_t)row * N_PART + p];
    if (ps.y > 0.f) {
      if (ps.x > m) { ss = ss * __expf(m - ps.x) + ps.y; m = ps.x; }
      else          { ss += ps.y * __expf(ps.x - m); }
    }
  }
  __shared__ float sm[256], sv[256];
  sm[t] = m; sv[t] = ss;
  __syncthreads();
  for (int o = 128; o > 0; o >>= 1) {
    if (t < o) {
      float m1 = sm[t], s1 = sv[t];
      float m2 = sm[t + o], s2 = sv[t + o];
      float mm = fmaxf(m1, m2);
      float e1 = (m1 > NEG_INF) ? s1 * __expf(m1 - mm) : 0.f;
      float e2 = (m2 > NEG_INF) ? s2 * __expf(m2 - mm) : 0.f;
      sm[t] = mm; sv[t] = e1 + e2;
    }
    __syncthreads();
  }
  if (t == 0) {
    float M = sm[0], S = sv[0];
    float2 zt = ZT[row];
    // swap the target's unmodified exp term for the margin-modified one
    S += __expf(zt.y - M) - __expf(zt.x - M);
    LOSSI[row] = M + logf(S) - zt.y;
  }
}

// ------- Pass E2: mean over 512 rows -> scalar loss -------------------------
__global__ __launch_bounds__(256) void k_mean(const float* __restrict__ LOSSI,
                                              float* __restrict__ OUT) {
  int t = threadIdx.x;
  float s_ = LOSSI[t] + LOSSI[t + 256];
#pragma unroll
  for (int m = 1; m <= 32; m <<= 1) s_ += __shfl_xor(s_, m);
  __shared__ float wsum[4];
  if ((t & 63) == 0) wsum[t >> 6] = s_;
  __syncthreads();
  if (t == 0) OUT[0] = (wsum[0] + wsum[1] + wsum[2] + wsum[3]) * (1.0f / 512.0f);
}

extern "C" void kernel_launch(void* const* d_in, const int* in_sizes, int n_in,
                              void* d_out, int out_size, void* d_ws, size_t ws_size,
                              hipStream_t stream) {
  const float* X   = (const float*)d_in[0];   // [512,512] f32
  const float* W   = (const float*)d_in[1];   // [85742,512] f32
  const int*   LBL = (const int*)d_in[2];     // [512] i32
  float* OUT = (float*)d_out;

  char* ws = (char*)d_ws;
  unsigned short* XN = (unsigned short*)ws;            // 512*512*2       = 524288
  float*  FN    = (float*)(ws + 524288);               // 512*4
  float2* ZT    = (float2*)(ws + 526336);              // 512*8
  float*  LOSSI = (float*)(ws + 530432);               // 512*4
  float2* PART  = (float2*)(ws + 532480);              // 512*1340*8 = 5488640
  unsigned short* WBF = (unsigned short*)(ws + 6021120);  // 85742*512*2 = 87799808
  float* RINV   = (float*)(ws + 93820928);             // 85742*4 = 342968
  const size_t NEED = 94163896;

  k_xnorm<<<dim3(128), dim3(256), 0, stream>>>(X, XN, FN);
  if (ws_size >= NEED) {
    k_wnorm<<<dim3((C_CLS + 3) / 4), dim3(256), 0, stream>>>(W, WBF, RINV);
    k_gemm2<<<dim3(2680), dim3(256), 0, stream>>>(WBF, XN, FN, RINV, PART);
  } else {
    k_gemm_fb<<<dim3(2680), dim3(256), 0, stream>>>(W, XN, FN, PART);
  }
  k_target<<<dim3(512), dim3(64),  0, stream>>>(W, XN, FN, LBL, ZT);
  k_lse   <<<dim3(512), dim3(256), 0, stream>>>(PART, ZT, LOSSI);
  k_mean  <<<dim3(1),   dim3(256), 0, stream>>>(LOSSI, OUT);
}